// Round 1
// baseline (391.842 us; speedup 1.0000x reference)
//
#include <hip/hip_runtime.h>
#include <stdint.h>
#include <stddef.h>

// Problem constants (from reference)
#define N_GRAM   4
#define D_STATE  16
#define N_SLOTS  500000
#define N_BLADES 8
#define N_POS    (8 * 8192)          // batch * seq
#define FNV_OFFSET 2166136261u
#define FNV_PRIME  16777619u

// Use native clang ext_vectors so __builtin_nontemporal_load/store accept them.
typedef float v4f __attribute__((ext_vector_type(4)));
typedef int   v4i __attribute__((ext_vector_type(4)));

// ============================================================================
// Phase 1: relayout bank [blade][slot][16f] -> ws [slot][blade][16f].
// Pure streaming: reads fully sequential per blade chunk, writes fully
// sequential, LDS-tiled transpose in between (XOR swizzle -> conflict-free).
// Cost: 244 MiB read + 244 MiB write, both at streaming rate.
// Payoff: each position's gather becomes ONE contiguous 512 B block instead of
// eight 64 B lines 32 MB apart (8x fewer DRAM row activations), and the
// freshly written ws is hot in Infinity Cache for phase 2.
// ============================================================================
#define TSLOTS 64   // slots per block; LDS tile = 64 * 512 B = 32 KiB

__global__ __launch_bounds__(256) void relayout_kernel(
    const v4f* __restrict__ bank4,   // [blade][slot][4 x f4]
    v4f* __restrict__ ws4)           // [slot][32 x f4]  (blade*4 + d4)
{
    __shared__ v4f lds[TSLOTS * 32];
    const int t  = threadIdx.x;
    const int s0 = blockIdx.x * TSLOTS;

    // Load: iteration i reads blade i's 4 KiB chunk for this slot range,
    // fully coalesced (256 lanes x 16 B contiguous).
    #pragma unroll
    for (int i = 0; i < 8; ++i) {
        const int idx   = i * 256 + t;      // [0, 2048)
        const int blade = idx >> 8;         // == i
        const int rem   = idx & 255;
        const int slot  = rem >> 2;
        const int d4    = rem & 3;
        const int gs    = s0 + slot;
        v4f v = {0.f, 0.f, 0.f, 0.f};
        if (gs < N_SLOTS)
            v = __builtin_nontemporal_load(
                    &bank4[(size_t)blade * (N_SLOTS * 4) + (size_t)gs * 4 + d4]);
        const int f = blade * 4 + d4;                       // logical f4 index in row
        lds[slot * 32 + (f ^ ((slot & 7) << 2))] = v;       // swizzled store
    }
    __syncthreads();

    // Store: fully sequential 32 KiB per block (256 lanes x 16 B contiguous).
    #pragma unroll
    for (int i = 0; i < 8; ++i) {
        const int idx  = i * 256 + t;       // [0, 2048)
        const int slot = idx >> 5;
        const int f    = idx & 31;
        const int gs   = s0 + slot;
        if (gs < N_SLOTS)
            ws4[(size_t)gs * 32 + f] = lds[slot * 32 + (f ^ ((slot & 7) << 2))];
    }
}

// ============================================================================
// Phase 2: gather. 32 threads per position; the wave's 2 positions now read
// two contiguous 512 B blocks from ws instead of 16 scattered 64 B lines.
// ============================================================================
__global__ __launch_bounds__(256) void gather_kernel(
    const v4i* __restrict__ tok4,        // token_window int32: [pos][4]
    const v4f* __restrict__ ws4,         // [slot][32 x f4]
    v4f* __restrict__ out4)              // [pos][32 x f4]
{
    const int tid = blockIdx.x * blockDim.x + threadIdx.x;
    const int pos = tid >> 5;
    const int sub = tid & 31;
    if (pos >= N_POS) return;

    const v4i tk = tok4[pos];   // wave-broadcast (16 B per position)

    uint32_t h = FNV_OFFSET;
    h = (h ^ (uint32_t)tk.x) * FNV_PRIME;
    h = (h ^ (uint32_t)tk.y) * FNV_PRIME;
    h = (h ^ (uint32_t)tk.z) * FNV_PRIME;
    h = (h ^ (uint32_t)tk.w) * FNV_PRIME;
    const uint32_t addr = h % (uint32_t)N_SLOTS;

    const v4f v = ws4[(size_t)addr * 32 + sub];
    // out is write-once, never re-read this iteration: nt store keeps it from
    // evicting the ws working set out of Infinity Cache.
    __builtin_nontemporal_store(v, &out4[(size_t)pos * 32 + sub]);
}

// ============================================================================
// Fallback: the previous verified direct kernel (used if ws is too small).
// ============================================================================
__global__ __launch_bounds__(256) void direct_kernel(
    const v4i* __restrict__ tok4,
    const v4f* __restrict__ bank4,
    v4f* __restrict__ out4)
{
    const int tid = blockIdx.x * blockDim.x + threadIdx.x;
    const int pos = tid >> 5;
    const int sub = tid & 31;
    if (pos >= N_POS) return;

    const v4i tk = tok4[pos];

    uint32_t h = FNV_OFFSET;
    h = (h ^ (uint32_t)tk.x) * FNV_PRIME;
    h = (h ^ (uint32_t)tk.y) * FNV_PRIME;
    h = (h ^ (uint32_t)tk.z) * FNV_PRIME;
    h = (h ^ (uint32_t)tk.w) * FNV_PRIME;
    const uint32_t addr = h % (uint32_t)N_SLOTS;

    const int blade = sub >> 2;
    const int d4    = sub & 3;
    const v4f v = bank4[(size_t)blade * ((size_t)N_SLOTS * 4) + (size_t)addr * 4 + d4];
    out4[(size_t)pos * 32 + sub] = v;
}

extern "C" void kernel_launch(void* const* d_in, const int* in_sizes, int n_in,
                              void* d_out, int out_size, void* d_ws, size_t ws_size,
                              hipStream_t stream) {
    const v4i* tok4  = (const v4i*)d_in[0];
    const v4f* bank4 = (const v4f*)d_in[1];
    v4f*       out4  = (v4f*)d_out;

    const size_t need = (size_t)N_SLOTS * N_BLADES * D_STATE * sizeof(float); // 256,000,000 B

    if (d_ws != nullptr && ws_size >= need) {
        v4f* ws4 = (v4f*)d_ws;
        const int grid1 = (N_SLOTS + TSLOTS - 1) / TSLOTS;   // 7813
        relayout_kernel<<<grid1, 256, 0, stream>>>(bank4, ws4);

        const int total_threads = N_POS * 32;                // 2,097,152
        const int grid2 = (total_threads + 255) / 256;       // 8192
        gather_kernel<<<grid2, 256, 0, stream>>>(tok4, ws4, out4);
    } else {
        const int total_threads = N_POS * 32;
        const int grid = (total_threads + 255) / 256;
        direct_kernel<<<grid, 256, 0, stream>>>(tok4, bank4, out4);
    }
}

// Round 2
// 310.616 us; speedup vs baseline: 1.2615x; 1.2615x over previous
//
#include <hip/hip_runtime.h>
#include <stdint.h>
#include <stddef.h>

// Problem constants (from reference)
#define N_GRAM   4
#define D_STATE  16
#define N_SLOTS  500000
#define N_BLADES 8
#define N_POS    (8 * 8192)          // batch * seq
#define FNV_OFFSET 2166136261u
#define FNV_PRIME  16777619u

typedef float v4f __attribute__((ext_vector_type(4)));
typedef int   v4i __attribute__((ext_vector_type(4)));

// Mapping: 32 threads per position.
//   sub = tid & 31 : blade = sub>>2, d4 = sub&3 (float4 index within D_STATE=16)
// Each thread: 1 float4 gather from bank + 1 coalesced float4 store to out.
//
// Evidence from rounds 0/1: making the random gather granule 8x coarser
// (512 B contiguous via a relayout pass) changed gather time by 0 us --
// the gather is NOT DRAM-granule-bound. dur_us floor (~300 us) is the
// harness's 1.024 GB workspace-poison fills (155-164 us each, visible as
// the only top-5 dispatches) inside the timed region; this kernel's own
// dispatch is <155 us (absent from top-5) and its traffic (~100 MB) is at
// streaming rate. So: minimum total work, single dispatch, no workspace.
__global__ __launch_bounds__(256) void TokenBladeBank_kernel(
    const v4i* __restrict__ tok4,        // token_window int32: [pos][4]
    const v4f* __restrict__ bank4,       // bank as float4: [blade][slot][4]
    v4f* __restrict__ out4)              // out as float4: [pos][blade][4]
{
    const int tid = blockIdx.x * blockDim.x + threadIdx.x;
    const int pos = tid >> 5;
    const int sub = tid & 31;
    if (pos >= N_POS) return;

    const v4i t = tok4[pos];   // wave-broadcast: 32 lanes of a position read same 16 B

    uint32_t h = FNV_OFFSET;
    h = (h ^ (uint32_t)t.x) * FNV_PRIME;
    h = (h ^ (uint32_t)t.y) * FNV_PRIME;
    h = (h ^ (uint32_t)t.z) * FNV_PRIME;
    h = (h ^ (uint32_t)t.w) * FNV_PRIME;
    const uint32_t addr = h % (uint32_t)N_SLOTS;

    const int blade = sub >> 2;
    const int d4    = sub & 3;

    // bank flat float4 index: blade * (N_SLOTS*4) + addr * 4 + d4
    const v4f v = bank4[(size_t)blade * ((size_t)N_SLOTS * 4) + (size_t)addr * 4 + d4];

    // out is write-once, never re-read: nontemporal store avoids evicting
    // bank lines from L2/L3 with the 32 MiB output stream.
    __builtin_nontemporal_store(v, &out4[(size_t)pos * 32 + sub]);
}

extern "C" void kernel_launch(void* const* d_in, const int* in_sizes, int n_in,
                              void* d_out, int out_size, void* d_ws, size_t ws_size,
                              hipStream_t stream) {
    const v4i* tok4  = (const v4i*)d_in[0];    // int32 tokens, 4 per position
    const v4f* bank4 = (const v4f*)d_in[1];    // fp32 bank
    v4f*       out4  = (v4f*)d_out;            // fp32 out

    const int total_threads = N_POS * 32;   // 2,097,152
    const int block = 256;
    const int grid = (total_threads + block - 1) / block;  // 8192

    TokenBladeBank_kernel<<<grid, block, 0, stream>>>(tok4, bank4, out4);
}